// Round 3
// baseline (108.456 us; speedup 1.0000x reference)
//
#include <hip/hip_runtime.h>

// DifferentiableRGBtoVel: image (4,3,512,512) fp32, cmap (256,3) fp32, v_i (256) fp32
// out velocities (4,512,512) fp32.
//
// v6 (occupancy + LDS-resident operands): logit_k = -K2*|c_k - p|^2 in exp2 units,
// computed on the matrix pipe (mfma_f32_16x16x32_bf16, 3-way bf16 splits, identical
// math to v5 which passed at absmax 0.0039). v5 stalled (VALUBusy 62%, occ 26%):
// 68 VGPRs forced per-tile global reloads of the B-table and no mfma->exp pipelining.
// v6: 1 M-tile per wave (16 px), B-table staged once into LDS (ds_read_b128 per tile),
// packed {s,sv} v_pk_fma_f32 accumulate, shfl_xor butterfly epilogue (no padded-LDS
// transpose -> no bank conflicts, single __syncthreads). Target: trans-pipe roofline.
//
// (Round-2 bench was a GPUAcquisitionTimeout — infra, not kernel. Resubmitting v6.)

typedef __attribute__((ext_vector_type(8))) short short8;   // 8 bf16 = 4 VGPRs
typedef __attribute__((ext_vector_type(4))) float f32x4;
typedef __attribute__((ext_vector_type(2))) float v2f;

#define HWSZ 262144              // 512*512
#define NPIX 1048576             // 4*512*512
#define K2F  144.2695040888963f  // 1/(0.01*ln2)

// round f32 -> bf16 bits (RNE); residual (exact in fp32) returned via *resid
static __device__ __forceinline__ unsigned f2bf(float x, float* resid) {
  unsigned u = __builtin_bit_cast(unsigned, x);
  unsigned r = (u + 0x7fffu + ((u >> 16) & 1u)) >> 16;
  if (resid) *resid = x - __builtin_bit_cast(float, r << 16);
  return r;
}
static __device__ __forceinline__ unsigned bfp(unsigned lo, unsigned hi) {
  return (lo & 0xffffu) | (hi << 16);
}

// ---- prep: build the B-fragment table (16 tiles x 64 lanes x 16B = 16 KiB) ----
// B-frag lane mapping for 16x16x32: col = lane&15 (color), k-chunk = lane>>4.
__global__ __launch_bounds__(256) void rgb2vel_prep(
    const float* __restrict__ cmap, float4* __restrict__ btab) {
  int k = threadIdx.x;  // 256 threads, 1 block
  float c0 = cmap[k * 3 + 0], c1 = cmap[k * 3 + 1], c2 = cmap[k * 3 + 2];
  float cc[3] = {c0, c1, c2};
  unsigned H[3], M[3], L[3];
  float r;
#pragma unroll
  for (int ch = 0; ch < 3; ++ch) {          // 3-way split of 2K2*c
    float x = 2.0f * K2F * cc[ch];
    H[ch] = f2bf(x, &r);
    M[ch] = f2bf(r, &r);
    L[ch] = f2bf(r, nullptr);
  }
  float mcc = -(K2F * (c0 * c0 + c1 * c1 + c2 * c2));
  unsigned mh = f2bf(mcc, &r);
  unsigned mm = f2bf(r, &r);
  unsigned ml = f2bf(r, nullptr);
  const unsigned N1 = 0xBF80u;  // -1.0 bf16
  unsigned d[16];
  d[0] = bfp(H[0], H[1]); d[1] = bfp(H[2], H[0]); d[2] = bfp(H[1], H[2]);
  d[3] = bfp(M[0], M[1]); d[4] = bfp(M[2], L[0]); d[5] = bfp(L[1], L[2]);
  d[6] = bfp(M[0], M[1]); d[7] = bfp(M[2], H[0]); d[8] = bfp(H[1], H[2]);
  d[9] = bfp(mh, mm);     d[10] = bfp(ml, N1);    d[11] = bfp(N1, N1);
  d[12] = d[13] = d[14] = d[15] = 0u;
  int col = k & 15, tt = k >> 4;
#pragma unroll
  for (int g = 0; g < 4; ++g) {
    float4 v;
    v.x = __builtin_bit_cast(float, d[4 * g + 0]);
    v.y = __builtin_bit_cast(float, d[4 * g + 1]);
    v.z = __builtin_bit_cast(float, d[4 * g + 2]);
    v.w = __builtin_bit_cast(float, d[4 * g + 3]);
    btab[tt * 64 + g * 16 + col] = v;
  }
}

// ---- main: 512 threads = 8 waves/block, 16 px/wave (1 M-tile), 128 px/block ----
__global__ __launch_bounds__(512, 6) void rgb2vel_main(
    const float* __restrict__ img, const float4* __restrict__ btab,
    const float* __restrict__ vv, float* __restrict__ out) {
  __shared__ __align__(16) unsigned char sA[128 * 80];  // A-rows, 80B stride (2-way max)
  __shared__ __align__(16) float4 sB[1024];             // btab copy, 16 KiB
  const int tid = threadIdx.x;
  const int lane = tid & 63;
  const int warp = tid >> 6;   // 0..7
  const int col = lane & 15;   // C column -> color within tile
  const int g = lane >> 4;     // k-chunk / row-group
  const int pb0 = blockIdx.x * 128;

  // btab -> LDS (512 threads x 2 float4)
  sB[tid] = btab[tid];
  sB[tid + 512] = btab[tid + 512];

  // stage 128 pixels as A-slot rows (threads 0..127, coalesced channel loads)
  if (tid < 128) {
    int idx = pb0 + tid;
    int n = idx >> 18;              // HWSZ = 2^18
    int hw = idx & (HWSZ - 1);
    const float* pb = img + (size_t)n * 3 * HWSZ + hw;
    float p0 = pb[0], p1 = pb[HWSZ], p2 = pb[2 * HWSZ];
    float pc[3] = {p0, p1, p2};
    unsigned ph[3], pm[3], pl[3];
    float r;
#pragma unroll
    for (int ch = 0; ch < 3; ++ch) {  // 3-way split of p
      ph[ch] = f2bf(pc[ch], &r);
      pm[ch] = f2bf(r, &r);
      pl[ch] = f2bf(r, nullptr);
    }
    float q = K2F * (p0 * p0 + p1 * p1 + p2 * p2);
    unsigned qh = f2bf(q, &r);
    unsigned qm = f2bf(r, &r);
    unsigned ql = f2bf(r, nullptr);
    const unsigned ONE = 0x3F80u;
    int4* sb = (int4*)(sA + tid * 80);
    sb[0] = make_int4((int)bfp(ph[0], ph[1]), (int)bfp(ph[2], pm[0]),
                      (int)bfp(pm[1], pm[2]), (int)bfp(ph[0], ph[1]));
    sb[1] = make_int4((int)bfp(ph[2], ph[0]), (int)bfp(ph[1], ph[2]),
                      (int)bfp(pm[0], pm[1]), (int)bfp(pm[2], pl[0]));
    sb[2] = make_int4((int)bfp(pl[1], pl[2]), (int)bfp(ONE, ONE),
                      (int)bfp(ONE, qh),      (int)bfp(qm, ql));
    sb[3] = make_int4(0, 0, 0, 0);
  }

  // v_k per tile for this lane's color column (hoisted, L1-cached)
  float vk[16];
#pragma unroll
  for (int t = 0; t < 16; ++t) vk[t] = vv[t * 16 + col];

  __syncthreads();

  // A-frag for this wave's single 16-px M-tile
  short8 afr = *(const short8*)(sA + (warp * 16 + col) * 80 + g * 16);

  // acc[rr] = {s, sv} for pixel row g*4+rr
  v2f acc0 = {0.f, 0.f}, acc1 = {0.f, 0.f}, acc2 = {0.f, 0.f}, acc3 = {0.f, 0.f};
  const f32x4 z = {0.f, 0.f, 0.f, 0.f};

#pragma unroll
  for (int t = 0; t < 16; ++t) {
    short8 bfr = __builtin_bit_cast(short8, sB[t * 64 + lane]);  // ds_read_b128
    f32x4 c = __builtin_amdgcn_mfma_f32_16x16x32_bf16(afr, bfr, z, 0, 0, 0);
    v2f cf = {1.0f, vk[t]};
    float w0 = __builtin_amdgcn_exp2f(c[0]);
    float w1 = __builtin_amdgcn_exp2f(c[1]);
    float w2 = __builtin_amdgcn_exp2f(c[2]);
    float w3 = __builtin_amdgcn_exp2f(c[3]);
    acc0 = __builtin_elementwise_fma((v2f){w0, w0}, cf, acc0);  // v_pk_fma_f32
    acc1 = __builtin_elementwise_fma((v2f){w1, w1}, cf, acc1);
    acc2 = __builtin_elementwise_fma((v2f){w2, w2}, cf, acc2);
    acc3 = __builtin_elementwise_fma((v2f){w3, w3}, cf, acc3);
  }

  // Reduce across the 16-lane color group (pixel g*4+rr lives at same rr in
  // lanes g*16..g*16+15): 4-step butterfly on low lane bits.
#pragma unroll
  for (int m = 1; m <= 8; m <<= 1) {
    acc0.x += __shfl_xor(acc0.x, m); acc0.y += __shfl_xor(acc0.y, m);
    acc1.x += __shfl_xor(acc1.x, m); acc1.y += __shfl_xor(acc1.y, m);
    acc2.x += __shfl_xor(acc2.x, m); acc2.y += __shfl_xor(acc2.y, m);
    acc3.x += __shfl_xor(acc3.x, m); acc3.y += __shfl_xor(acc3.y, m);
  }
  if (col < 4) {
    v2f a = (col == 0) ? acc0 : (col == 1) ? acc1 : (col == 2) ? acc2 : acc3;
    out[pb0 + warp * 16 + g * 4 + col] = a.y / a.x;
  }
}

extern "C" void kernel_launch(void* const* d_in, const int* in_sizes, int n_in,
                              void* d_out, int out_size, void* d_ws, size_t ws_size,
                              hipStream_t stream) {
  const float* image = (const float*)d_in[0];  // (4,3,512,512)
  const float* cmap  = (const float*)d_in[1];  // (256,3)
  const float* v_i   = (const float*)d_in[2];  // (256,)
  float* out = (float*)d_out;                  // (4,512,512)

  float4* btab = (float4*)d_ws;                // 16 KiB B-frag table

  rgb2vel_prep<<<1, 256, 0, stream>>>(cmap, btab);
  rgb2vel_main<<<NPIX / 128, 512, 0, stream>>>(image, btab, v_i, out);
}

// Round 5
// 100.592 us; speedup vs baseline: 1.0782x; 1.0782x over previous
//
#include <hip/hip_runtime.h>
#include <hip/hip_fp16.h>

// DifferentiableRGBtoVel: image (4,3,512,512) fp32, cmap (256,3) fp32, v_i (256) fp32
// out velocities (4,512,512) fp32.
//
// v8b (dual-MFMA, single kernel; fixes round-4 cvt_pkrtz return-type compile error
// by bit_casting the builtin's 2x__fp16 result to unsigned and union-packing):
//
// logit'_k = 14 - K2*|c_k - p|^2 in exp2 units (bias +14 cancels in the softmax
// ratio; keeps small w out of f16 subnormals).
//
// MFMA #1 (bf16, 3-way splits, same 24-slot scheme as v5/v6 which passed):
//   D1[row=color][col=pixel] = logit'.  Lane l holds 4 logits of pixel (l&15),
//   colors t*16 + (l>>4)*4 + rr.
// exp2 -> w (f32, <= 2^14) -> v_cvt_pkrtz f16 pairs.
// MFMA #2 (f16): D2[row=pixel][col] += W_chunk x Bv, Bv col0 = 1, col1 = v_k.
//   C-accumulator sums across all 8 K=32 chunks -> s and s*v on the matrix pipe;
//   no per-k VALU accumulate, no butterfly epilogue.
//   Slot->color permutation (built into sBv): chunk u, slot 8g+j  <->
//   color (2u + (j>>2))*16 + g*4 + (j&3)   [matches what lane 16g+c holds from
//   tiles 2u,2u+1: regs = {cvt(w0,w1),cvt(w2,w3)} of each tile].
// D2 layout: lane 16g+c holds rows g*4+rr, col c: c=0 -> s, c=1 -> s*v.
//   shfl_xor(1) pairs them; lanes c==0 store 4 pixels each.
//
// All tables (color A-frags 16K, reduction Bv 8K) built per-block in LDS from
// cmap/v_i behind the existing staging barrier -> prep kernel + d_ws removed.
//
// Perf model (fits v4/v5/v6): v_exp_f32 ~16cy/wave64 -> exp issue floor 27.3 us;
// v6's extra 6.8 us of pk_fma and ~20 us of stall are what v8 removes.

typedef __attribute__((ext_vector_type(8))) short short8;     // 8 bf16
typedef __attribute__((ext_vector_type(8))) _Float16 f16x8;   // 8 f16
typedef __attribute__((ext_vector_type(4))) float f32x4;

#define HWSZ 262144              // 512*512
#define NPIX 1048576             // 4*512*512
#define K2F  144.2695040888963f  // 1/(0.01*ln2)
#define BIASF 14.0f              // logit bias (cancels in ratio)

// round f32 -> bf16 bits (RNE); residual (exact in fp32) returned via *resid
static __device__ __forceinline__ unsigned f2bf(float x, float* resid) {
  unsigned u = __builtin_bit_cast(unsigned, x);
  unsigned r = (u + 0x7fffu + ((u >> 16) & 1u)) >> 16;
  if (resid) *resid = x - __builtin_bit_cast(float, r << 16);
  return r;
}
static __device__ __forceinline__ unsigned bfp(unsigned lo, unsigned hi) {
  return (lo & 0xffffu) | (hi << 16);
}
// pack two f32 -> one dword of two RTZ f16 (v_cvt_pkrtz_f16_f32)
static __device__ __forceinline__ unsigned pkrtz(float a, float b) {
  return __builtin_bit_cast(unsigned, __builtin_amdgcn_cvt_pkrtz(a, b));
}

__global__ __launch_bounds__(512, 8) void rgb2vel_main(
    const float* __restrict__ img, const float* __restrict__ cmap,
    const float* __restrict__ vv, float* __restrict__ out) {
  __shared__ __align__(16) unsigned char sA[128 * 80];  // pixel B-frag rows
  __shared__ __align__(16) int4 sB4[1024];              // color A-frag table 16K
  __shared__ __align__(16) int4 sBv4[512];              // reduction Bv table 8K
  const int tid = threadIdx.x;
  const int lane = tid & 63;
  const int warp = tid >> 6;   // 0..7
  const int c = lane & 15;     // pixel-in-tile (D1 col / D2 row-group owner)
  const int g = lane >> 4;     // k-chunk index
  const int pb0 = blockIdx.x * 128;

  // ---- build color A-frag table (threads 0..255, one color each) ----
  if (tid < 256) {
    int k = tid;
    float c0 = cmap[k * 3 + 0], c1 = cmap[k * 3 + 1], c2 = cmap[k * 3 + 2];
    float cc[3] = {c0, c1, c2};
    unsigned H[3], M[3], L[3];
    float r;
#pragma unroll
    for (int ch = 0; ch < 3; ++ch) {          // 3-way split of 2K2*c
      float x = 2.0f * K2F * cc[ch];
      H[ch] = f2bf(x, &r);
      M[ch] = f2bf(r, &r);
      L[ch] = f2bf(r, nullptr);
    }
    float mcc = BIASF - K2F * (c0 * c0 + c1 * c1 + c2 * c2);
    unsigned mh = f2bf(mcc, &r);
    unsigned mm = f2bf(r, &r);
    unsigned ml = f2bf(r, nullptr);
    const unsigned N1 = 0xBF80u;  // -1.0 bf16
    unsigned d[16];
    d[0] = bfp(H[0], H[1]); d[1] = bfp(H[2], H[0]); d[2] = bfp(H[1], H[2]);
    d[3] = bfp(M[0], M[1]); d[4] = bfp(M[2], L[0]); d[5] = bfp(L[1], L[2]);
    d[6] = bfp(M[0], M[1]); d[7] = bfp(M[2], H[0]); d[8] = bfp(H[1], H[2]);
    d[9] = bfp(mh, mm);     d[10] = bfp(ml, N1);    d[11] = bfp(N1, N1);
    d[12] = d[13] = d[14] = d[15] = 0u;
    int col = k & 15, tt = k >> 4;
#pragma unroll
    for (int g2 = 0; g2 < 4; ++g2)
      sB4[tt * 64 + g2 * 16 + col] =
          make_int4((int)d[4 * g2 + 0], (int)d[4 * g2 + 1],
                    (int)d[4 * g2 + 2], (int)d[4 * g2 + 3]);
  }

  // ---- build reduction Bv table (all 512 threads, one 16B entry each) ----
  {
    int u = tid >> 6, l = tid & 63, cc2 = l & 15, gg = l >> 4;
    int4 q = make_int4(0, 0, 0, 0);
    if (cc2 == 0) {
      q = make_int4(0x3C003C00, 0x3C003C00, 0x3C003C00, 0x3C003C00);  // 1.0h x8
    } else if (cc2 == 1) {
      unsigned hq[4];
#pragma unroll
      for (int jp = 0; jp < 4; ++jp) {
        int j0 = 2 * jp, j1 = 2 * jp + 1;
        int i0 = (2 * u + (j0 >> 2)) * 16 + gg * 4 + (j0 & 3);
        int i1 = (2 * u + (j1 >> 2)) * 16 + gg * 4 + (j1 & 3);
        unsigned h0 = (unsigned)__half_as_ushort(__float2half(vv[i0]));  // RNE
        unsigned h1 = (unsigned)__half_as_ushort(__float2half(vv[i1]));
        hq[jp] = h0 | (h1 << 16);
      }
      q = make_int4((int)hq[0], (int)hq[1], (int)hq[2], (int)hq[3]);
    }
    sBv4[tid] = q;
  }

  // ---- stage 128 pixels as B-frag rows (threads 384..511) ----
  if (tid >= 384) {
    int px = tid & 127;
    int idx = pb0 + px;
    int n = idx >> 18;              // HWSZ = 2^18
    int hw = idx & (HWSZ - 1);
    const float* pbp = img + (size_t)n * 3 * HWSZ + hw;
    float p0 = pbp[0], p1 = pbp[HWSZ], p2 = pbp[2 * HWSZ];
    float pc[3] = {p0, p1, p2};
    unsigned ph[3], pm[3], pl[3];
    float r;
#pragma unroll
    for (int ch = 0; ch < 3; ++ch) {  // 3-way split of p
      ph[ch] = f2bf(pc[ch], &r);
      pm[ch] = f2bf(r, &r);
      pl[ch] = f2bf(r, nullptr);
    }
    float qv = K2F * (p0 * p0 + p1 * p1 + p2 * p2);
    unsigned qh = f2bf(qv, &r);
    unsigned qm = f2bf(r, &r);
    unsigned ql = f2bf(r, nullptr);
    const unsigned ONE = 0x3F80u;
    int4* sb = (int4*)(sA + px * 80);
    sb[0] = make_int4((int)bfp(ph[0], ph[1]), (int)bfp(ph[2], pm[0]),
                      (int)bfp(pm[1], pm[2]), (int)bfp(ph[0], ph[1]));
    sb[1] = make_int4((int)bfp(ph[2], ph[0]), (int)bfp(ph[1], ph[2]),
                      (int)bfp(pm[0], pm[1]), (int)bfp(pm[2], pl[0]));
    sb[2] = make_int4((int)bfp(pl[1], pl[2]), (int)bfp(ONE, ONE),
                      (int)bfp(ONE, qh),      (int)bfp(qm, ql));
    sb[3] = make_int4(0, 0, 0, 0);
  }
  __syncthreads();

  // pixel B-frag: lane supplies B1[slots 8g..8g+8)[col=c] = pixel (warp*16+c)
  short8 pfr = *(const short8*)(sA + (warp * 16 + c) * 80 + g * 16);

  f32x4 acc = {0.f, 0.f, 0.f, 0.f};
  const f32x4 z = {0.f, 0.f, 0.f, 0.f};

#pragma unroll
  for (int u = 0; u < 8; ++u) {
    short8 ca = __builtin_bit_cast(short8, sB4[(2 * u) * 64 + lane]);
    short8 cb = __builtin_bit_cast(short8, sB4[(2 * u + 1) * 64 + lane]);
    f32x4 d0 = __builtin_amdgcn_mfma_f32_16x16x32_bf16(ca, pfr, z, 0, 0, 0);
    f32x4 d1 = __builtin_amdgcn_mfma_f32_16x16x32_bf16(cb, pfr, z, 0, 0, 0);
    union { unsigned w[4]; f16x8 v8; } wu;
    wu.w[0] = pkrtz(__builtin_amdgcn_exp2f(d0[0]), __builtin_amdgcn_exp2f(d0[1]));
    wu.w[1] = pkrtz(__builtin_amdgcn_exp2f(d0[2]), __builtin_amdgcn_exp2f(d0[3]));
    wu.w[2] = pkrtz(__builtin_amdgcn_exp2f(d1[0]), __builtin_amdgcn_exp2f(d1[1]));
    wu.w[3] = pkrtz(__builtin_amdgcn_exp2f(d1[2]), __builtin_amdgcn_exp2f(d1[3]));
    f16x8 bv = __builtin_bit_cast(f16x8, sBv4[u * 64 + lane]);
    acc = __builtin_amdgcn_mfma_f32_16x16x32_f16(wu.v8, bv, acc, 0, 0, 0);
  }

  // lane 16g+0 holds s, lane 16g+1 holds s*v for pixels g*4+rr
  float p0 = __shfl_xor(acc[0], 1);
  float p1 = __shfl_xor(acc[1], 1);
  float p2 = __shfl_xor(acc[2], 1);
  float p3 = __shfl_xor(acc[3], 1);
  if (c == 0) {
    float* o = out + pb0 + warp * 16 + g * 4;
    o[0] = p0 / acc[0];
    o[1] = p1 / acc[1];
    o[2] = p2 / acc[2];
    o[3] = p3 / acc[3];
  }
}

extern "C" void kernel_launch(void* const* d_in, const int* in_sizes, int n_in,
                              void* d_out, int out_size, void* d_ws, size_t ws_size,
                              hipStream_t stream) {
  const float* image = (const float*)d_in[0];  // (4,3,512,512)
  const float* cmap  = (const float*)d_in[1];  // (256,3)
  const float* v_i   = (const float*)d_in[2];  // (256,)
  float* out = (float*)d_out;                  // (4,512,512)

  rgb2vel_main<<<NPIX / 128, 512, 0, stream>>>(image, cmap, v_i, out);
}

// Round 6
// 97.893 us; speedup vs baseline: 1.1079x; 1.0276x over previous
//
#include <hip/hip_runtime.h>
#include <hip/hip_fp16.h>

// DifferentiableRGBtoVel: image (4,3,512,512) fp32, cmap (256,3) fp32, v_i (256) fp32
// out velocities (4,512,512) fp32.
//
// v9 (2 M-tiles/wave + max occupancy): logit'_k = 14 - K2*|c_k - p|^2 in exp2
// units (bias cancels in the softmax ratio; keeps w out of f16 subnormals).
// Same verified dual-MFMA math as v8b (absmax 0.0039):
//   MFMA #1 bf16 (3-way splits, 24-slot scheme) -> logits, lane l holds 4 logits
//   of pixel (l&15); exp2 -> v_cvt_pkrtz f16; MFMA #2 f16 vs Bv (col0=1, col1=v_k)
//   accumulates s and s*v on the matrix pipe across all 8 K=32 chunks.
// v8b post-mortem: VALU busy (33.7us) == trans-pipe floor (268M v_exp_f32 @
// ~16cy/wave64 = 27.3us + cvt 3.4 + prologue ~3); remaining 13us is issue-idle:
// per-block table rebuild over only 128px + a single serial mfma->exp chain/wave.
// v9: 256 px/block (two independent chains per wave share ca/cb/bv reads;
// prologue+tail amortized 2x) and LDS sized to exactly 4 blocks/CU (40960*4 =
// 163840 = full LDS) -> 32 waves/CU.

typedef __attribute__((ext_vector_type(8))) short short8;     // 8 bf16
typedef __attribute__((ext_vector_type(8))) _Float16 f16x8;   // 8 f16
typedef __attribute__((ext_vector_type(4))) float f32x4;

#define HWSZ 262144              // 512*512
#define NPIX 1048576             // 4*512*512
#define K2F  144.2695040888963f  // 1/(0.01*ln2)
#define BIASF 14.0f              // logit bias (cancels in ratio)
#define PXB  256                 // pixels per block

// round f32 -> bf16 bits (RNE); residual (exact in fp32) returned via *resid
static __device__ __forceinline__ unsigned f2bf(float x, float* resid) {
  unsigned u = __builtin_bit_cast(unsigned, x);
  unsigned r = (u + 0x7fffu + ((u >> 16) & 1u)) >> 16;
  if (resid) *resid = x - __builtin_bit_cast(float, r << 16);
  return r;
}
static __device__ __forceinline__ unsigned bfp(unsigned lo, unsigned hi) {
  return (lo & 0xffffu) | (hi << 16);
}
// pack two f32 -> one dword of two RTZ f16 (v_cvt_pkrtz_f16_f32)
static __device__ __forceinline__ unsigned pkrtz(float a, float b) {
  return __builtin_bit_cast(unsigned, __builtin_amdgcn_cvt_pkrtz(a, b));
}

__global__ __launch_bounds__(512, 8) void rgb2vel_main(
    const float* __restrict__ img, const float* __restrict__ cmap,
    const float* __restrict__ vv, float* __restrict__ out) {
  __shared__ __align__(16) int4 sA4[PXB * 4];  // pixel B-frag rows, 64B stride: 16K
  __shared__ __align__(16) int4 sB4[1024];     // color A-frag table: 16K
  __shared__ __align__(16) int4 sBv4[512];     // reduction Bv table: 8K
  const int tid = threadIdx.x;
  const int lane = tid & 63;
  const int warp = tid >> 6;   // 0..7
  const int c = lane & 15;     // pixel-in-tile (D1 col / D2 row-group owner)
  const int g = lane >> 4;     // k-chunk index
  const int pb0 = blockIdx.x * PXB;

  if (tid < 256) {
    // ---- color A-frag table (one color per thread) ----
    int k = tid;
    float c0 = cmap[k * 3 + 0], c1 = cmap[k * 3 + 1], c2 = cmap[k * 3 + 2];
    float cc[3] = {c0, c1, c2};
    unsigned H[3], M[3], L[3];
    float r;
#pragma unroll
    for (int ch = 0; ch < 3; ++ch) {          // 3-way split of 2K2*c
      float x = 2.0f * K2F * cc[ch];
      H[ch] = f2bf(x, &r);
      M[ch] = f2bf(r, &r);
      L[ch] = f2bf(r, nullptr);
    }
    float mcc = BIASF - K2F * (c0 * c0 + c1 * c1 + c2 * c2);
    unsigned mh = f2bf(mcc, &r);
    unsigned mm = f2bf(r, &r);
    unsigned ml = f2bf(r, nullptr);
    const unsigned N1 = 0xBF80u;  // -1.0 bf16
    unsigned d[16];
    d[0] = bfp(H[0], H[1]); d[1] = bfp(H[2], H[0]); d[2] = bfp(H[1], H[2]);
    d[3] = bfp(M[0], M[1]); d[4] = bfp(M[2], L[0]); d[5] = bfp(L[1], L[2]);
    d[6] = bfp(M[0], M[1]); d[7] = bfp(M[2], H[0]); d[8] = bfp(H[1], H[2]);
    d[9] = bfp(mh, mm);     d[10] = bfp(ml, N1);    d[11] = bfp(N1, N1);
    d[12] = d[13] = d[14] = d[15] = 0u;
    int col = k & 15, tt = k >> 4;
#pragma unroll
    for (int g2 = 0; g2 < 4; ++g2)
      sB4[tt * 64 + g2 * 16 + col] =
          make_int4((int)d[4 * g2 + 0], (int)d[4 * g2 + 1],
                    (int)d[4 * g2 + 2], (int)d[4 * g2 + 3]);
  } else {
    // ---- stage 256 pixels as B-frag rows (threads 256..511) ----
    int px = tid - 256;
    int idx = pb0 + px;
    int n = idx >> 18;              // HWSZ = 2^18
    int hw = idx & (HWSZ - 1);
    const float* pbp = img + (size_t)n * 3 * HWSZ + hw;
    float p0 = pbp[0], p1 = pbp[HWSZ], p2 = pbp[2 * HWSZ];
    float pc[3] = {p0, p1, p2};
    unsigned ph[3], pm[3], pl[3];
    float r;
#pragma unroll
    for (int ch = 0; ch < 3; ++ch) {  // 3-way split of p
      ph[ch] = f2bf(pc[ch], &r);
      pm[ch] = f2bf(r, &r);
      pl[ch] = f2bf(r, nullptr);
    }
    float qv = K2F * (p0 * p0 + p1 * p1 + p2 * p2);
    unsigned qh = f2bf(qv, &r);
    unsigned qm = f2bf(r, &r);
    unsigned ql = f2bf(r, nullptr);
    const unsigned ONE = 0x3F80u;
    int4* sb = &sA4[px * 4];
    sb[0] = make_int4((int)bfp(ph[0], ph[1]), (int)bfp(ph[2], pm[0]),
                      (int)bfp(pm[1], pm[2]), (int)bfp(ph[0], ph[1]));
    sb[1] = make_int4((int)bfp(ph[2], ph[0]), (int)bfp(ph[1], ph[2]),
                      (int)bfp(pm[0], pm[1]), (int)bfp(pm[2], pl[0]));
    sb[2] = make_int4((int)bfp(pl[1], pl[2]), (int)bfp(ONE, ONE),
                      (int)bfp(ONE, qh),      (int)bfp(qm, ql));
    sb[3] = make_int4(0, 0, 0, 0);
  }

  // ---- reduction Bv table (all 512 threads, one 16B entry each) ----
  {
    int u = tid >> 6, l = tid & 63, cc2 = l & 15, gg = l >> 4;
    int4 q = make_int4(0, 0, 0, 0);
    if (cc2 == 0) {
      q = make_int4(0x3C003C00, 0x3C003C00, 0x3C003C00, 0x3C003C00);  // 1.0h x8
    } else if (cc2 == 1) {
      unsigned hq[4];
#pragma unroll
      for (int jp = 0; jp < 4; ++jp) {
        int j0 = 2 * jp, j1 = 2 * jp + 1;
        int i0 = (2 * u + (j0 >> 2)) * 16 + gg * 4 + (j0 & 3);
        int i1 = (2 * u + (j1 >> 2)) * 16 + gg * 4 + (j1 & 3);
        unsigned h0 = (unsigned)__half_as_ushort(__float2half(vv[i0]));  // RNE
        unsigned h1 = (unsigned)__half_as_ushort(__float2half(vv[i1]));
        hq[jp] = h0 | (h1 << 16);
      }
      q = make_int4((int)hq[0], (int)hq[1], (int)hq[2], (int)hq[3]);
    }
    sBv4[tid] = q;
  }
  __syncthreads();

  // two pixel B-frags per wave: tiles at px warp*16 and 128+warp*16
  short8 pfr0 = __builtin_bit_cast(short8, sA4[(warp * 16 + c) * 4 + g]);
  short8 pfr1 = __builtin_bit_cast(short8, sA4[(128 + warp * 16 + c) * 4 + g]);

  f32x4 accA = {0.f, 0.f, 0.f, 0.f};
  f32x4 accB = {0.f, 0.f, 0.f, 0.f};
  const f32x4 z = {0.f, 0.f, 0.f, 0.f};

#pragma unroll
  for (int u = 0; u < 8; ++u) {
    short8 ca = __builtin_bit_cast(short8, sB4[(2 * u) * 64 + lane]);
    short8 cb = __builtin_bit_cast(short8, sB4[(2 * u + 1) * 64 + lane]);
    f32x4 d0a = __builtin_amdgcn_mfma_f32_16x16x32_bf16(ca, pfr0, z, 0, 0, 0);
    f32x4 d1a = __builtin_amdgcn_mfma_f32_16x16x32_bf16(cb, pfr0, z, 0, 0, 0);
    f32x4 d0b = __builtin_amdgcn_mfma_f32_16x16x32_bf16(ca, pfr1, z, 0, 0, 0);
    f32x4 d1b = __builtin_amdgcn_mfma_f32_16x16x32_bf16(cb, pfr1, z, 0, 0, 0);
    union { unsigned w[4]; f16x8 v8; } wa, wb;
    wa.w[0] = pkrtz(__builtin_amdgcn_exp2f(d0a[0]), __builtin_amdgcn_exp2f(d0a[1]));
    wa.w[1] = pkrtz(__builtin_amdgcn_exp2f(d0a[2]), __builtin_amdgcn_exp2f(d0a[3]));
    wa.w[2] = pkrtz(__builtin_amdgcn_exp2f(d1a[0]), __builtin_amdgcn_exp2f(d1a[1]));
    wa.w[3] = pkrtz(__builtin_amdgcn_exp2f(d1a[2]), __builtin_amdgcn_exp2f(d1a[3]));
    wb.w[0] = pkrtz(__builtin_amdgcn_exp2f(d0b[0]), __builtin_amdgcn_exp2f(d0b[1]));
    wb.w[1] = pkrtz(__builtin_amdgcn_exp2f(d0b[2]), __builtin_amdgcn_exp2f(d0b[3]));
    wb.w[2] = pkrtz(__builtin_amdgcn_exp2f(d1b[0]), __builtin_amdgcn_exp2f(d1b[1]));
    wb.w[3] = pkrtz(__builtin_amdgcn_exp2f(d1b[2]), __builtin_amdgcn_exp2f(d1b[3]));
    f16x8 bv = __builtin_bit_cast(f16x8, sBv4[u * 64 + lane]);
    accA = __builtin_amdgcn_mfma_f32_16x16x32_f16(wa.v8, bv, accA, 0, 0, 0);
    accB = __builtin_amdgcn_mfma_f32_16x16x32_f16(wb.v8, bv, accB, 0, 0, 0);
  }

  // lane 16g+0 holds s, lane 16g+1 holds s*v for pixel rows g*4+rr (both tiles)
  float a0 = __shfl_xor(accA[0], 1);
  float a1 = __shfl_xor(accA[1], 1);
  float a2 = __shfl_xor(accA[2], 1);
  float a3 = __shfl_xor(accA[3], 1);
  float b0 = __shfl_xor(accB[0], 1);
  float b1 = __shfl_xor(accB[1], 1);
  float b2 = __shfl_xor(accB[2], 1);
  float b3 = __shfl_xor(accB[3], 1);
  if (c == 0) {
    float* oA = out + pb0 + warp * 16 + g * 4;
    oA[0] = a0 / accA[0];
    oA[1] = a1 / accA[1];
    oA[2] = a2 / accA[2];
    oA[3] = a3 / accA[3];
    float* oB = out + pb0 + 128 + warp * 16 + g * 4;
    oB[0] = b0 / accB[0];
    oB[1] = b1 / accB[1];
    oB[2] = b2 / accB[2];
    oB[3] = b3 / accB[3];
  }
}

extern "C" void kernel_launch(void* const* d_in, const int* in_sizes, int n_in,
                              void* d_out, int out_size, void* d_ws, size_t ws_size,
                              hipStream_t stream) {
  const float* image = (const float*)d_in[0];  // (4,3,512,512)
  const float* cmap  = (const float*)d_in[1];  // (256,3)
  const float* v_i   = (const float*)d_in[2];  // (256,)
  float* out = (float*)d_out;                  // (4,512,512)

  rgb2vel_main<<<NPIX / PXB, 512, 0, stream>>>(image, cmap, v_i, out);
}